// Round 7
// baseline (745.799 us; speedup 1.0000x reference)
//
#include <hip/hip_runtime.h>
#include <hip/hip_bf16.h>

// Problem constants (MoE grouped FFN, uniform groups)
#define NE 32      // experts
#define HD 2048    // hidden
#define ID 1024    // intermediate
#define GT 1024    // tokens per expert (T/E = 32768/32)

#define BK 64

typedef __attribute__((ext_vector_type(8))) __bf16 bf16x8;
typedef __attribute__((ext_vector_type(4))) float  f32x4;

__device__ __forceinline__ __bf16 f2b(float f) { return (__bf16)f; }

__device__ __forceinline__ bf16x8 pack8(const f32x4 a, const f32x4 b) {
  bf16x8 v;
  v[0] = f2b(a[0]); v[1] = f2b(a[1]); v[2] = f2b(a[2]); v[3] = f2b(a[3]);
  v[4] = f2b(b[0]); v[5] = f2b(b[1]); v[6] = f2b(b[2]); v[7] = f2b(b[3]);
  return v;
}

// ---------------------------------------------------------------------------
// Kernel 1: gate_up = x_e @ w13_e ; h = silu(gate)*up  (bf16 out to ws)
// BM=128, BN=64 (gate & up each 64 wide). 256 threads = 4 waves (2x2).
// SINGLE-BARRIER double-buffered pipeline:
//   iter: MFMA(buf p, kk=0) | cvt+ds_write tile k+1 -> buf p^1 |
//         MFMA(buf p, kk=32) | issue loads k+2 | lgkmcnt(0)+s_barrier
// ds_writes overlap MFMAs (different buffer); waves not phase-locked.
// LDS XOR swizzle (R2/R3 counter-verified):
//   A:  As[p][row][(oct ^ (row&7))*8 + j]
//   B:  Bg/Bu[p][row][(oct ^ ((row>>1)&7))*8 + j]
// ---------------------------------------------------------------------------
__global__ __launch_bounds__(256, 2)
void moe_gemm1_swiglu(const float* __restrict__ x,
                      const float* __restrict__ w13,
                      __bf16* __restrict__ h) {
  __shared__ __bf16 As[2][128][BK];
  __shared__ __bf16 Bg[2][64][BK];
  __shared__ __bf16 Bu[2][64][BK];

  const int t  = threadIdx.x;
  const int e  = blockIdx.z;
  const int m0 = blockIdx.y * 128;
  const int n0 = blockIdx.x * 64;

  const float* xA = x   + (size_t)(e * GT + m0) * HD;
  const float* wB = w13 + (size_t)e * HD * (2 * ID);

  const int wid = t >> 6, lane = t & 63;
  const int wm = wid >> 1, wn = wid & 1;   // 2x2 waves: 64 rows x 32 cols each
  const int fr = lane & 15, fq = lane >> 4;

  // B staging ownership: threads 0-127 stage Bg, 128-255 stage Bu
  const int tb = t & 127;
  const int nq = tb & 15;        // n-quad 0..15 (4 cols over 64)
  const int ko = tb >> 4;        // k-octet 0..7 (8 k-rows)
  const int bcol = (t < 128 ? 0 : ID) + n0 + nq * 4;
  __bf16 (*Bm)[64][BK] = (t < 128) ? Bg : Bu;

  f32x4 accg[4][2];
  f32x4 accu[4][2];
#pragma unroll
  for (int i = 0; i < 4; ++i)
#pragma unroll
    for (int j = 0; j < 2; ++j) { accg[i][j] = 0.f; accu[i][j] = 0.f; }

  // prefetch registers: A 32 + B 32 = 64 VGPRs
  f32x4 ra[4][2];
  f32x4 rb[8];

#define LOAD_TILE1(K0)                                                         \
  do {                                                                         \
    _Pragma("unroll")                                                          \
    for (int i = 0; i < 4; ++i) {                                              \
      int id = i * 256 + t;                                                    \
      int r = id >> 3, oc = id & 7;                                            \
      const float* src = xA + (size_t)r * HD + (K0) + oc * 8;                  \
      ra[i][0] = *reinterpret_cast<const f32x4*>(src);                         \
      ra[i][1] = *reinterpret_cast<const f32x4*>(src + 4);                     \
    }                                                                          \
    const float* pb = wB + (size_t)((K0) + ko * 8) * (2 * ID) + bcol;          \
    _Pragma("unroll")                                                          \
    for (int j = 0; j < 8; ++j)                                                \
      rb[j] = *reinterpret_cast<const f32x4*>(pb + (size_t)j * (2 * ID));      \
  } while (0)

#define STORE_TILE1(P)                                                         \
  do {                                                                         \
    _Pragma("unroll")                                                          \
    for (int i = 0; i < 4; ++i) {                                              \
      int id = i * 256 + t;                                                    \
      int r = id >> 3, oc = id & 7;                                            \
      *reinterpret_cast<bf16x8*>(&As[P][r][(oc ^ (r & 7)) * 8]) =              \
          pack8(ra[i][0], ra[i][1]);                                           \
    }                                                                          \
    _Pragma("unroll")                                                          \
    for (int c = 0; c < 4; ++c) {                                              \
      int row = nq * 4 + c;                                                    \
      int slot = (ko ^ ((row >> 1) & 7)) * 8;                                  \
      bf16x8 v;                                                                \
      _Pragma("unroll")                                                        \
      for (int j = 0; j < 8; ++j) v[j] = f2b(rb[j][c]);                        \
      *reinterpret_cast<bf16x8*>(&Bm[P][row][slot]) = v;                       \
    }                                                                          \
  } while (0)

#define MFMA_HALF1(P, KB)                                                      \
  do {                                                                         \
    bf16x8 af[4], bgf[2], buf2[2];                                             \
    _Pragma("unroll")                                                          \
    for (int mi = 0; mi < 4; ++mi) {                                           \
      int row = wm * 64 + mi * 16 + fr;                                        \
      int oct = (fq + (KB)) ^ (row & 7);                                       \
      af[mi] = *reinterpret_cast<const bf16x8*>(&As[P][row][oct * 8]);         \
    }                                                                          \
    _Pragma("unroll")                                                          \
    for (int ni = 0; ni < 2; ++ni) {                                           \
      int row = wn * 32 + ni * 16 + fr;                                        \
      int oct = (fq + (KB)) ^ ((row >> 1) & 7);                                \
      bgf[ni]  = *reinterpret_cast<const bf16x8*>(&Bg[P][row][oct * 8]);       \
      buf2[ni] = *reinterpret_cast<const bf16x8*>(&Bu[P][row][oct * 8]);       \
    }                                                                          \
    __builtin_amdgcn_s_setprio(1);                                             \
    _Pragma("unroll")                                                          \
    for (int mi = 0; mi < 4; ++mi)                                             \
      _Pragma("unroll")                                                        \
      for (int ni = 0; ni < 2; ++ni) {                                         \
        accg[mi][ni] = __builtin_amdgcn_mfma_f32_16x16x32_bf16(                \
            af[mi], bgf[ni], accg[mi][ni], 0, 0, 0);                           \
        accu[mi][ni] = __builtin_amdgcn_mfma_f32_16x16x32_bf16(                \
            af[mi], buf2[ni], accu[mi][ni], 0, 0, 0);                          \
      }                                                                        \
    __builtin_amdgcn_s_setprio(0);                                             \
  } while (0)

  // prologue: stage tile 0, prefetch tile 1
  LOAD_TILE1(0);
  STORE_TILE1(0);
  LOAD_TILE1(BK);
  asm volatile("s_waitcnt lgkmcnt(0)" ::: "memory");
  __builtin_amdgcn_s_barrier();

  for (int k0 = 0, p = 0; k0 < HD; k0 += BK, p ^= 1) {
    MFMA_HALF1(p, 0);
    if (k0 + BK < HD) STORE_TILE1(p ^ 1);      // overlaps MFMA (other buffer)
    MFMA_HALF1(p, 4);
    if (k0 + 2 * BK < HD) LOAD_TILE1(k0 + 2 * BK);
    asm volatile("s_waitcnt lgkmcnt(0)" ::: "memory");
    __builtin_amdgcn_s_barrier();
  }
#undef LOAD_TILE1
#undef STORE_TILE1
#undef MFMA_HALF1

  // ---- epilogue: SwiGLU (in-wave), write h (bf16) ----
#pragma unroll
  for (int mi = 0; mi < 4; ++mi)
#pragma unroll
    for (int ni = 0; ni < 2; ++ni)
#pragma unroll
      for (int j = 0; j < 4; ++j) {
        int row = m0 + wm * 64 + mi * 16 + fq * 4 + j;
        int col = n0 + wn * 32 + ni * 16 + fr;
        float g = accg[mi][ni][j];
        float u = accu[mi][ni][j];
        float s = g / (1.f + __expf(-g));
        h[(size_t)(e * GT + row) * ID + col] = f2b(s * u);
      }
}

// ---------------------------------------------------------------------------
// Kernel 2: out = h @ w2_e   (h bf16 [T][I], w2 f32 [E][I][H], out f32)
// grid (HD/128=16, GT/128=8, NE=32), 256 threads. Same single-barrier dbuf.
// ---------------------------------------------------------------------------
__global__ __launch_bounds__(256, 2)
void moe_gemm2(const __bf16* __restrict__ h,
               const float* __restrict__ w2,
               float* __restrict__ out) {
  __shared__ __bf16 As[2][128][BK];
  __shared__ __bf16 Bs[2][128][BK];

  const int t  = threadIdx.x;
  const int e  = blockIdx.z;
  const int m0 = blockIdx.y * 128;
  const int n0 = blockIdx.x * 128;

  const __bf16* hA = h  + (size_t)(e * GT + m0) * ID;
  const float*  wB = w2 + (size_t)e * ID * HD;

  const int wid = t >> 6, lane = t & 63;
  const int wm = wid >> 1, wn = wid & 1;
  const int fr = lane & 15, fq = lane >> 4;

  const int nq = t & 31;
  const int ko = t >> 5;

  f32x4 acc[4][4];
#pragma unroll
  for (int i = 0; i < 4; ++i)
#pragma unroll
    for (int j = 0; j < 4; ++j) acc[i][j] = 0.f;

  bf16x8 raa[4];
  f32x4 rb[8];

#define LOAD_TILE2(K0)                                                         \
  do {                                                                         \
    _Pragma("unroll")                                                          \
    for (int i = 0; i < 4; ++i) {                                              \
      int id = i * 256 + t;                                                    \
      int koA = id & 7, m = id >> 3;                                           \
      raa[i] = *reinterpret_cast<const bf16x8*>(hA + (size_t)m * ID + (K0) + koA * 8); \
    }                                                                          \
    const float* pg = wB + (size_t)((K0) + ko * 8) * HD + (n0 + nq * 4);       \
    _Pragma("unroll")                                                          \
    for (int j = 0; j < 8; ++j)                                                \
      rb[j] = *reinterpret_cast<const f32x4*>(pg + (size_t)j * HD);            \
  } while (0)

#define STORE_TILE2(P)                                                         \
  do {                                                                         \
    _Pragma("unroll")                                                          \
    for (int i = 0; i < 4; ++i) {                                              \
      int id = i * 256 + t;                                                    \
      int koA = id & 7, m = id >> 3;                                           \
      *reinterpret_cast<bf16x8*>(&As[P][m][(koA ^ (m & 7)) * 8]) = raa[i];     \
    }                                                                          \
    _Pragma("unroll")                                                          \
    for (int c = 0; c < 4; ++c) {                                              \
      int row = nq * 4 + c;                                                    \
      int slot = (ko ^ ((row >> 1) & 7)) * 8;                                  \
      bf16x8 v;                                                                \
      _Pragma("unroll")                                                        \
      for (int j = 0; j < 8; ++j) v[j] = f2b(rb[j][c]);                        \
      *reinterpret_cast<bf16x8*>(&Bs[P][row][slot]) = v;                       \
    }                                                                          \
  } while (0)

#define MFMA_HALF2(P, KB)                                                      \
  do {                                                                         \
    bf16x8 af[4], bf[4];                                                       \
    _Pragma("unroll")                                                          \
    for (int mi = 0; mi < 4; ++mi) {                                           \
      int row = wm * 64 + mi * 16 + fr;                                        \
      int oct = (fq + (KB)) ^ (row & 7);                                       \
      af[mi] = *reinterpret_cast<const bf16x8*>(&As[P][row][oct * 8]);         \
    }                                                                          \
    _Pragma("unroll")                                                          \
    for (int ni = 0; ni < 4; ++ni) {                                           \
      int row = wn * 64 + ni * 16 + fr;                                        \
      int oct = (fq + (KB)) ^ ((row >> 1) & 7);                                \
      bf[ni] = *reinterpret_cast<const bf16x8*>(&Bs[P][row][oct * 8]);         \
    }                                                                          \
    __builtin_amdgcn_s_setprio(1);                                             \
    _Pragma("unroll")                                                          \
    for (int mi = 0; mi < 4; ++mi)                                             \
      _Pragma("unroll")                                                        \
      for (int ni = 0; ni < 4; ++ni)                                           \
        acc[mi][ni] = __builtin_amdgcn_mfma_f32_16x16x32_bf16(                 \
            af[mi], bf[ni], acc[mi][ni], 0, 0, 0);                             \
    __builtin_amdgcn_s_setprio(0);                                             \
  } while (0)

  LOAD_TILE2(0);
  STORE_TILE2(0);
  LOAD_TILE2(BK);
  asm volatile("s_waitcnt lgkmcnt(0)" ::: "memory");
  __builtin_amdgcn_s_barrier();

  for (int k0 = 0, p = 0; k0 < ID; k0 += BK, p ^= 1) {
    MFMA_HALF2(p, 0);
    if (k0 + BK < ID) STORE_TILE2(p ^ 1);
    MFMA_HALF2(p, 4);
    if (k0 + 2 * BK < ID) LOAD_TILE2(k0 + 2 * BK);
    asm volatile("s_waitcnt lgkmcnt(0)" ::: "memory");
    __builtin_amdgcn_s_barrier();
  }
#undef LOAD_TILE2
#undef STORE_TILE2
#undef MFMA_HALF2

  // ---- epilogue: f32 store ----
#pragma unroll
  for (int mi = 0; mi < 4; ++mi)
#pragma unroll
    for (int ni = 0; ni < 4; ++ni)
#pragma unroll
      for (int j = 0; j < 4; ++j) {
        int row = m0 + wm * 64 + mi * 16 + fq * 4 + j;
        int col = n0 + wn * 64 + ni * 16 + fr;
        out[(size_t)(e * GT + row) * HD + col] = acc[mi][ni][j];
      }
}

extern "C" void kernel_launch(void* const* d_in, const int* in_sizes, int n_in,
                              void* d_out, int out_size, void* d_ws, size_t ws_size,
                              hipStream_t stream) {
  const float* x   = (const float*)d_in[0];
  const float* w13 = (const float*)d_in[1];
  const float* w2  = (const float*)d_in[2];
  float* out = (float*)d_out;
  __bf16* h = (__bf16*)d_ws;   // T x I bf16 = 64 MiB scratch

  moe_gemm1_swiglu<<<dim3(ID / 64, GT / 128, NE), dim3(256), 0, stream>>>(x, w13, h);
  moe_gemm2<<<dim3(HD / 128, GT / 128, NE), dim3(256), 0, stream>>>(h, w2, out);
}

// Round 8
// 705.347 us; speedup vs baseline: 1.0574x; 1.0574x over previous
//
#include <hip/hip_runtime.h>
#include <hip/hip_bf16.h>

// Problem constants (MoE grouped FFN, uniform groups)
#define NE 32      // experts
#define HD 2048    // hidden
#define ID 1024    // intermediate
#define GT 1024    // tokens per expert (T/E = 32768/32)

#define BK 64

typedef __attribute__((ext_vector_type(8))) __bf16 bf16x8;
typedef __attribute__((ext_vector_type(4))) float  f32x4;

__device__ __forceinline__ __bf16 f2b(float f) { return (__bf16)f; }

__device__ __forceinline__ bf16x8 pack8(const f32x4 a, const f32x4 b) {
  bf16x8 v;
  v[0] = f2b(a[0]); v[1] = f2b(a[1]); v[2] = f2b(a[2]); v[3] = f2b(a[3]);
  v[4] = f2b(b[0]); v[5] = f2b(b[1]); v[6] = f2b(b[2]); v[7] = f2b(b[3]);
  return v;
}

// ---------------------------------------------------------------------------
// Prepass: x (f32, T*H) -> x_bf16 in ws. Memory-bound streaming, 8 elem/thread.
// Bit-identical to the in-loop f2b conversion it replaces.
// ---------------------------------------------------------------------------
__global__ __launch_bounds__(256)
void cvt_x_bf16(const float* __restrict__ x, __bf16* __restrict__ xb) {
  size_t i = ((size_t)blockIdx.x * 256 + threadIdx.x) * 8;
  f32x4 a = *reinterpret_cast<const f32x4*>(x + i);
  f32x4 b = *reinterpret_cast<const f32x4*>(x + i + 4);
  *reinterpret_cast<bf16x8*>(xb + i) = pack8(a, b);
}

// ---------------------------------------------------------------------------
// Kernel 1 (bf16-A variant): gate_up = x_e @ w13_e ; h = silu(gate)*up
// BM=128, BN=64 (gate & up each 64 wide). 256 threads = 4 waves (2x2).
// A-path identical to gemm2's proven shape: 4x bf16x8 load + 4 swizzled
// ds_write, zero cvt. B-path (f32 w13 + cvt) unchanged from R7.
// Single-barrier dbuf loop kept verbatim from R7.
// LDS XOR swizzle (R2/R3 counter-verified).
// ---------------------------------------------------------------------------
__global__ __launch_bounds__(256, 2)
void moe_gemm1_swiglu_bA(const __bf16* __restrict__ xb,
                         const float* __restrict__ w13,
                         __bf16* __restrict__ h) {
  __shared__ __bf16 As[2][128][BK];
  __shared__ __bf16 Bg[2][64][BK];
  __shared__ __bf16 Bu[2][64][BK];

  const int t  = threadIdx.x;
  const int e  = blockIdx.z;
  const int m0 = blockIdx.y * 128;
  const int n0 = blockIdx.x * 64;

  const __bf16* xA = xb + (size_t)(e * GT + m0) * HD;
  const float*  wB = w13 + (size_t)e * HD * (2 * ID);

  const int wid = t >> 6, lane = t & 63;
  const int wm = wid >> 1, wn = wid & 1;   // 2x2 waves: 64 rows x 32 cols each
  const int fr = lane & 15, fq = lane >> 4;

  // B staging ownership: threads 0-127 stage Bg, 128-255 stage Bu
  const int tb = t & 127;
  const int nq = tb & 15;        // n-quad 0..15 (4 cols over 64)
  const int ko = tb >> 4;        // k-octet 0..7 (8 k-rows)
  const int bcol = (t < 128 ? 0 : ID) + n0 + nq * 4;
  __bf16 (*Bm)[64][BK] = (t < 128) ? Bg : Bu;

  f32x4 accg[4][2];
  f32x4 accu[4][2];
#pragma unroll
  for (int i = 0; i < 4; ++i)
#pragma unroll
    for (int j = 0; j < 2; ++j) { accg[i][j] = 0.f; accu[i][j] = 0.f; }

  bf16x8 raa[4];
  f32x4 rb[8];

#define LOAD_TILE1(K0)                                                         \
  do {                                                                         \
    _Pragma("unroll")                                                          \
    for (int i = 0; i < 4; ++i) {                                              \
      int id = i * 256 + t;                                                    \
      int koA = id & 7, m = id >> 3;                                           \
      raa[i] = *reinterpret_cast<const bf16x8*>(xA + (size_t)m * HD + (K0) + koA * 8); \
    }                                                                          \
    const float* pb = wB + (size_t)((K0) + ko * 8) * (2 * ID) + bcol;          \
    _Pragma("unroll")                                                          \
    for (int j = 0; j < 8; ++j)                                                \
      rb[j] = *reinterpret_cast<const f32x4*>(pb + (size_t)j * (2 * ID));      \
  } while (0)

#define STORE_TILE1(P)                                                         \
  do {                                                                         \
    _Pragma("unroll")                                                          \
    for (int i = 0; i < 4; ++i) {                                              \
      int id = i * 256 + t;                                                    \
      int koA = id & 7, m = id >> 3;                                           \
      *reinterpret_cast<bf16x8*>(&As[P][m][(koA ^ (m & 7)) * 8]) = raa[i];     \
    }                                                                          \
    _Pragma("unroll")                                                          \
    for (int c = 0; c < 4; ++c) {                                              \
      int row = nq * 4 + c;                                                    \
      int slot = (ko ^ ((row >> 1) & 7)) * 8;                                  \
      bf16x8 v;                                                                \
      _Pragma("unroll")                                                        \
      for (int j = 0; j < 8; ++j) v[j] = f2b(rb[j][c]);                        \
      *reinterpret_cast<bf16x8*>(&Bm[P][row][slot]) = v;                       \
    }                                                                          \
  } while (0)

#define MFMA_HALF1(P, KB)                                                      \
  do {                                                                         \
    bf16x8 af[4], bgf[2], buf2[2];                                             \
    _Pragma("unroll")                                                          \
    for (int mi = 0; mi < 4; ++mi) {                                           \
      int row = wm * 64 + mi * 16 + fr;                                        \
      int oct = (fq + (KB)) ^ (row & 7);                                       \
      af[mi] = *reinterpret_cast<const bf16x8*>(&As[P][row][oct * 8]);         \
    }                                                                          \
    _Pragma("unroll")                                                          \
    for (int ni = 0; ni < 2; ++ni) {                                           \
      int row = wn * 32 + ni * 16 + fr;                                        \
      int oct = (fq + (KB)) ^ ((row >> 1) & 7);                                \
      bgf[ni]  = *reinterpret_cast<const bf16x8*>(&Bg[P][row][oct * 8]);       \
      buf2[ni] = *reinterpret_cast<const bf16x8*>(&Bu[P][row][oct * 8]);       \
    }                                                                          \
    __builtin_amdgcn_s_setprio(1);                                             \
    _Pragma("unroll")                                                          \
    for (int mi = 0; mi < 4; ++mi)                                             \
      _Pragma("unroll")                                                        \
      for (int ni = 0; ni < 2; ++ni) {                                         \
        accg[mi][ni] = __builtin_amdgcn_mfma_f32_16x16x32_bf16(                \
            af[mi], bgf[ni], accg[mi][ni], 0, 0, 0);                           \
        accu[mi][ni] = __builtin_amdgcn_mfma_f32_16x16x32_bf16(                \
            af[mi], buf2[ni], accu[mi][ni], 0, 0, 0);                          \
      }                                                                        \
    __builtin_amdgcn_s_setprio(0);                                             \
  } while (0)

  LOAD_TILE1(0);
  STORE_TILE1(0);
  LOAD_TILE1(BK);
  asm volatile("s_waitcnt lgkmcnt(0)" ::: "memory");
  __builtin_amdgcn_s_barrier();

  for (int k0 = 0, p = 0; k0 < HD; k0 += BK, p ^= 1) {
    MFMA_HALF1(p, 0);
    if (k0 + BK < HD) STORE_TILE1(p ^ 1);
    MFMA_HALF1(p, 4);
    if (k0 + 2 * BK < HD) LOAD_TILE1(k0 + 2 * BK);
    asm volatile("s_waitcnt lgkmcnt(0)" ::: "memory");
    __builtin_amdgcn_s_barrier();
  }
#undef LOAD_TILE1
#undef STORE_TILE1
#undef MFMA_HALF1

#pragma unroll
  for (int mi = 0; mi < 4; ++mi)
#pragma unroll
    for (int ni = 0; ni < 2; ++ni)
#pragma unroll
      for (int j = 0; j < 4; ++j) {
        int row = m0 + wm * 64 + mi * 16 + fq * 4 + j;
        int col = n0 + wn * 32 + ni * 16 + fr;
        float g = accg[mi][ni][j];
        float u = accu[mi][ni][j];
        float s = g / (1.f + __expf(-g));
        h[(size_t)(e * GT + row) * ID + col] = f2b(s * u);
      }
}

// ---------------------------------------------------------------------------
// Kernel 1 fallback (f32 A, R7 verbatim) — used only if ws_size too small.
// ---------------------------------------------------------------------------
__global__ __launch_bounds__(256, 2)
void moe_gemm1_swiglu(const float* __restrict__ x,
                      const float* __restrict__ w13,
                      __bf16* __restrict__ h) {
  __shared__ __bf16 As[2][128][BK];
  __shared__ __bf16 Bg[2][64][BK];
  __shared__ __bf16 Bu[2][64][BK];

  const int t  = threadIdx.x;
  const int e  = blockIdx.z;
  const int m0 = blockIdx.y * 128;
  const int n0 = blockIdx.x * 64;

  const float* xA = x   + (size_t)(e * GT + m0) * HD;
  const float* wB = w13 + (size_t)e * HD * (2 * ID);

  const int wid = t >> 6, lane = t & 63;
  const int wm = wid >> 1, wn = wid & 1;
  const int fr = lane & 15, fq = lane >> 4;

  const int tb = t & 127;
  const int nq = tb & 15;
  const int ko = tb >> 4;
  const int bcol = (t < 128 ? 0 : ID) + n0 + nq * 4;
  __bf16 (*Bm)[64][BK] = (t < 128) ? Bg : Bu;

  f32x4 accg[4][2];
  f32x4 accu[4][2];
#pragma unroll
  for (int i = 0; i < 4; ++i)
#pragma unroll
    for (int j = 0; j < 2; ++j) { accg[i][j] = 0.f; accu[i][j] = 0.f; }

  f32x4 ra[4][2];
  f32x4 rb[8];

#define LOAD_TILE1(K0)                                                         \
  do {                                                                         \
    _Pragma("unroll")                                                          \
    for (int i = 0; i < 4; ++i) {                                              \
      int id = i * 256 + t;                                                    \
      int r = id >> 3, oc = id & 7;                                            \
      const float* src = xA + (size_t)r * HD + (K0) + oc * 8;                  \
      ra[i][0] = *reinterpret_cast<const f32x4*>(src);                         \
      ra[i][1] = *reinterpret_cast<const f32x4*>(src + 4);                     \
    }                                                                          \
    const float* pb = wB + (size_t)((K0) + ko * 8) * (2 * ID) + bcol;          \
    _Pragma("unroll")                                                          \
    for (int j = 0; j < 8; ++j)                                                \
      rb[j] = *reinterpret_cast<const f32x4*>(pb + (size_t)j * (2 * ID));      \
  } while (0)

#define STORE_TILE1(P)                                                         \
  do {                                                                         \
    _Pragma("unroll")                                                          \
    for (int i = 0; i < 4; ++i) {                                              \
      int id = i * 256 + t;                                                    \
      int r = id >> 3, oc = id & 7;                                            \
      *reinterpret_cast<bf16x8*>(&As[P][r][(oc ^ (r & 7)) * 8]) =              \
          pack8(ra[i][0], ra[i][1]);                                           \
    }                                                                          \
    _Pragma("unroll")                                                          \
    for (int c = 0; c < 4; ++c) {                                              \
      int row = nq * 4 + c;                                                    \
      int slot = (ko ^ ((row >> 1) & 7)) * 8;                                  \
      bf16x8 v;                                                                \
      _Pragma("unroll")                                                        \
      for (int j = 0; j < 8; ++j) v[j] = f2b(rb[j][c]);                        \
      *reinterpret_cast<bf16x8*>(&Bm[P][row][slot]) = v;                       \
    }                                                                          \
  } while (0)

#define MFMA_HALF1(P, KB)                                                      \
  do {                                                                         \
    bf16x8 af[4], bgf[2], buf2[2];                                             \
    _Pragma("unroll")                                                          \
    for (int mi = 0; mi < 4; ++mi) {                                           \
      int row = wm * 64 + mi * 16 + fr;                                        \
      int oct = (fq + (KB)) ^ (row & 7);                                       \
      af[mi] = *reinterpret_cast<const bf16x8*>(&As[P][row][oct * 8]);         \
    }                                                                          \
    _Pragma("unroll")                                                          \
    for (int ni = 0; ni < 2; ++ni) {                                           \
      int row = wn * 32 + ni * 16 + fr;                                        \
      int oct = (fq + (KB)) ^ ((row >> 1) & 7);                                \
      bgf[ni]  = *reinterpret_cast<const bf16x8*>(&Bg[P][row][oct * 8]);       \
      buf2[ni] = *reinterpret_cast<const bf16x8*>(&Bu[P][row][oct * 8]);       \
    }                                                                          \
    __builtin_amdgcn_s_setprio(1);                                             \
    _Pragma("unroll")                                                          \
    for (int mi = 0; mi < 4; ++mi)                                             \
      _Pragma("unroll")                                                        \
      for (int ni = 0; ni < 2; ++ni) {                                         \
        accg[mi][ni] = __builtin_amdgcn_mfma_f32_16x16x32_bf16(                \
            af[mi], bgf[ni], accg[mi][ni], 0, 0, 0);                           \
        accu[mi][ni] = __builtin_amdgcn_mfma_f32_16x16x32_bf16(                \
            af[mi], buf2[ni], accu[mi][ni], 0, 0, 0);                          \
      }                                                                        \
    __builtin_amdgcn_s_setprio(0);                                             \
  } while (0)

  LOAD_TILE1(0);
  STORE_TILE1(0);
  LOAD_TILE1(BK);
  asm volatile("s_waitcnt lgkmcnt(0)" ::: "memory");
  __builtin_amdgcn_s_barrier();

  for (int k0 = 0, p = 0; k0 < HD; k0 += BK, p ^= 1) {
    MFMA_HALF1(p, 0);
    if (k0 + BK < HD) STORE_TILE1(p ^ 1);
    MFMA_HALF1(p, 4);
    if (k0 + 2 * BK < HD) LOAD_TILE1(k0 + 2 * BK);
    asm volatile("s_waitcnt lgkmcnt(0)" ::: "memory");
    __builtin_amdgcn_s_barrier();
  }
#undef LOAD_TILE1
#undef STORE_TILE1
#undef MFMA_HALF1

#pragma unroll
  for (int mi = 0; mi < 4; ++mi)
#pragma unroll
    for (int ni = 0; ni < 2; ++ni)
#pragma unroll
      for (int j = 0; j < 4; ++j) {
        int row = m0 + wm * 64 + mi * 16 + fq * 4 + j;
        int col = n0 + wn * 32 + ni * 16 + fr;
        float g = accg[mi][ni][j];
        float u = accu[mi][ni][j];
        float s = g / (1.f + __expf(-g));
        h[(size_t)(e * GT + row) * ID + col] = f2b(s * u);
      }
}

// ---------------------------------------------------------------------------
// Kernel 2: out = h @ w2_e (R7 verbatim; measured 3320-cyc slot / ~776 TF)
// ---------------------------------------------------------------------------
__global__ __launch_bounds__(256, 2)
void moe_gemm2(const __bf16* __restrict__ h,
               const float* __restrict__ w2,
               float* __restrict__ out) {
  __shared__ __bf16 As[2][128][BK];
  __shared__ __bf16 Bs[2][128][BK];

  const int t  = threadIdx.x;
  const int e  = blockIdx.z;
  const int m0 = blockIdx.y * 128;
  const int n0 = blockIdx.x * 128;

  const __bf16* hA = h  + (size_t)(e * GT + m0) * ID;
  const float*  wB = w2 + (size_t)e * ID * HD;

  const int wid = t >> 6, lane = t & 63;
  const int wm = wid >> 1, wn = wid & 1;
  const int fr = lane & 15, fq = lane >> 4;

  const int nq = t & 31;
  const int ko = t >> 5;

  f32x4 acc[4][4];
#pragma unroll
  for (int i = 0; i < 4; ++i)
#pragma unroll
    for (int j = 0; j < 4; ++j) acc[i][j] = 0.f;

  bf16x8 raa[4];
  f32x4 rb[8];

#define LOAD_TILE2(K0)                                                         \
  do {                                                                         \
    _Pragma("unroll")                                                          \
    for (int i = 0; i < 4; ++i) {                                              \
      int id = i * 256 + t;                                                    \
      int koA = id & 7, m = id >> 3;                                           \
      raa[i] = *reinterpret_cast<const bf16x8*>(hA + (size_t)m * ID + (K0) + koA * 8); \
    }                                                                          \
    const float* pg = wB + (size_t)((K0) + ko * 8) * HD + (n0 + nq * 4);       \
    _Pragma("unroll")                                                          \
    for (int j = 0; j < 8; ++j)                                                \
      rb[j] = *reinterpret_cast<const f32x4*>(pg + (size_t)j * HD);            \
  } while (0)

#define STORE_TILE2(P)                                                         \
  do {                                                                         \
    _Pragma("unroll")                                                          \
    for (int i = 0; i < 4; ++i) {                                              \
      int id = i * 256 + t;                                                    \
      int koA = id & 7, m = id >> 3;                                           \
      *reinterpret_cast<bf16x8*>(&As[P][m][(koA ^ (m & 7)) * 8]) = raa[i];     \
    }                                                                          \
    _Pragma("unroll")                                                          \
    for (int c = 0; c < 4; ++c) {                                              \
      int row = nq * 4 + c;                                                    \
      int slot = (ko ^ ((row >> 1) & 7)) * 8;                                  \
      bf16x8 v;                                                                \
      _Pragma("unroll")                                                        \
      for (int j = 0; j < 8; ++j) v[j] = f2b(rb[j][c]);                        \
      *reinterpret_cast<bf16x8*>(&Bs[P][row][slot]) = v;                       \
    }                                                                          \
  } while (0)

#define MFMA_HALF2(P, KB)                                                      \
  do {                                                                         \
    bf16x8 af[4], bf[4];                                                       \
    _Pragma("unroll")                                                          \
    for (int mi = 0; mi < 4; ++mi) {                                           \
      int row = wm * 64 + mi * 16 + fr;                                        \
      int oct = (fq + (KB)) ^ (row & 7);                                       \
      af[mi] = *reinterpret_cast<const bf16x8*>(&As[P][row][oct * 8]);         \
    }                                                                          \
    _Pragma("unroll")                                                          \
    for (int ni = 0; ni < 4; ++ni) {                                           \
      int row = wn * 64 + ni * 16 + fr;                                        \
      int oct = (fq + (KB)) ^ ((row >> 1) & 7);                                \
      bf[ni] = *reinterpret_cast<const bf16x8*>(&Bs[P][row][oct * 8]);         \
    }                                                                          \
    __builtin_amdgcn_s_setprio(1);                                             \
    _Pragma("unroll")                                                          \
    for (int mi = 0; mi < 4; ++mi)                                             \
      _Pragma("unroll")                                                        \
      for (int ni = 0; ni < 4; ++ni)                                           \
        acc[mi][ni] = __builtin_amdgcn_mfma_f32_16x16x32_bf16(                 \
            af[mi], bf[ni], acc[mi][ni], 0, 0, 0);                             \
    __builtin_amdgcn_s_setprio(0);                                             \
  } while (0)

  LOAD_TILE2(0);
  STORE_TILE2(0);
  LOAD_TILE2(BK);
  asm volatile("s_waitcnt lgkmcnt(0)" ::: "memory");
  __builtin_amdgcn_s_barrier();

  for (int k0 = 0, p = 0; k0 < ID; k0 += BK, p ^= 1) {
    MFMA_HALF2(p, 0);
    if (k0 + BK < ID) STORE_TILE2(p ^ 1);
    MFMA_HALF2(p, 4);
    if (k0 + 2 * BK < ID) LOAD_TILE2(k0 + 2 * BK);
    asm volatile("s_waitcnt lgkmcnt(0)" ::: "memory");
    __builtin_amdgcn_s_barrier();
  }
#undef LOAD_TILE2
#undef STORE_TILE2
#undef MFMA_HALF2

#pragma unroll
  for (int mi = 0; mi < 4; ++mi)
#pragma unroll
    for (int ni = 0; ni < 4; ++ni)
#pragma unroll
      for (int j = 0; j < 4; ++j) {
        int row = m0 + wm * 64 + mi * 16 + fq * 4 + j;
        int col = n0 + wn * 64 + ni * 16 + fr;
        out[(size_t)(e * GT + row) * HD + col] = acc[mi][ni][j];
      }
}

extern "C" void kernel_launch(void* const* d_in, const int* in_sizes, int n_in,
                              void* d_out, int out_size, void* d_ws, size_t ws_size,
                              hipStream_t stream) {
  const float* x   = (const float*)d_in[0];
  const float* w13 = (const float*)d_in[1];
  const float* w2  = (const float*)d_in[2];
  float* out = (float*)d_out;

  // ws layout: h [0, 64 MiB) ; x_bf16 [64 MiB, 192 MiB+64 MiB)
  const size_t H_BYTES  = (size_t)GT * NE * ID * sizeof(__bf16);   // 64 MiB
  const size_t XB_BYTES = (size_t)GT * NE * HD * sizeof(__bf16);   // 128 MiB
  __bf16* h  = (__bf16*)d_ws;
  __bf16* xb = (__bf16*)((char*)d_ws + H_BYTES);

  if (ws_size >= H_BYTES + XB_BYTES) {
    // prepass: 67.1M f32 -> bf16, 8 elem/thread
    cvt_x_bf16<<<dim3((GT * NE * (HD / 8)) / 256), dim3(256), 0, stream>>>(x, xb);
    moe_gemm1_swiglu_bA<<<dim3(ID / 64, GT / 128, NE), dim3(256), 0, stream>>>(xb, w13, h);
  } else {
    moe_gemm1_swiglu<<<dim3(ID / 64, GT / 128, NE), dim3(256), 0, stream>>>(x, w13, h);
  }
  moe_gemm2<<<dim3(HD / 128, GT / 128, NE), dim3(256), 0, stream>>>(h, w2, out);
}